// Round 1
// baseline (4003.018 us; speedup 1.0000x reference)
//
#include <hip/hip_runtime.h>
#include <math.h>

#define N_ROWS 16384
#define M_ROWS 16384
#define DIM    512

#define TI 64
#define TJ 128
#define KB 32
#define LDA 68   // 64 + 4 pad (keeps 16B alignment, breaks store bank aliasing)
#define LDB 132  // 128 + 4 pad

// ---------------- Kernel A: row sums of squares (x_sq, y_sq) ----------------
__global__ __launch_bounds__(256) void rowsq_kernel(const float* __restrict__ x,
                                                    const float* __restrict__ y,
                                                    float* __restrict__ x_sq,
                                                    float* __restrict__ y_sq) {
    int wave = threadIdx.x >> 6;  // 0..3
    int lane = threadIdx.x & 63;
    int row  = blockIdx.x * 4 + wave;  // 0 .. N+M-1
    const float* src;
    float* dst;
    if (row < N_ROWS) { src = x + (size_t)row * DIM;            dst = x_sq + row; }
    else              { src = y + (size_t)(row - N_ROWS) * DIM; dst = y_sq + (row - N_ROWS); }
    const float4* s4 = (const float4*)src;
    float4 a = s4[lane * 2];
    float4 b = s4[lane * 2 + 1];
    float s = a.x*a.x + a.y*a.y + a.z*a.z + a.w*a.w
            + b.x*b.x + b.y*b.y + b.z*b.z + b.w*b.w;
    #pragma unroll
    for (int off = 32; off > 0; off >>= 1) s += __shfl_down(s, off, 64);
    if (lane == 0) *dst = s;
}

// ---------------- Kernel B: tiled -2*x@y^T + y_sq, min over j ----------------
// part[i*2 + jhalf] = min over this half's j of (y_sq[j] - 2*dot(x_i, y_j))
__global__ __launch_bounds__(256) void minred_kernel(const float* __restrict__ x,
                                                     const float* __restrict__ y,
                                                     const float* __restrict__ y_sq,
                                                     float* __restrict__ part) {
    __shared__ __align__(16) float As[KB * LDA];  // [k][i]
    __shared__ __align__(16) float Bs[KB * LDB];  // [k][j]
    __shared__ float red[TI][17];

    int t  = threadIdx.x;
    int tx = t & 15;   // j group: 8 cols each
    int ty = t >> 4;   // i group: 4 rows each
    int i0 = blockIdx.x * TI;
    int jhalf = blockIdx.y;
    int jbase = jhalf * (M_ROWS / 2);

    float minv[4] = {__builtin_inff(), __builtin_inff(), __builtin_inff(), __builtin_inff()};

    int srow = t >> 3;        // 0..31
    int skq  = (t & 7) * 4;   // 0,4,...,28

    for (int jt = 0; jt < (M_ROWS / 2) / TJ; ++jt) {
        int j0 = jbase + jt * TJ;
        float acc[4][8];
        #pragma unroll
        for (int c = 0; c < 4; ++c)
            #pragma unroll
            for (int d = 0; d < 8; ++d) acc[c][d] = 0.f;

        for (int kc = 0; kc < DIM; kc += KB) {
            // stage A tile (transposed): rows i0..i0+63, cols kc..kc+31
            #pragma unroll
            for (int it = 0; it < 2; ++it) {
                int row = it * 32 + srow;
                float4 v = *(const float4*)(x + (size_t)(i0 + row) * DIM + kc + skq);
                As[(skq + 0) * LDA + row] = v.x;
                As[(skq + 1) * LDA + row] = v.y;
                As[(skq + 2) * LDA + row] = v.z;
                As[(skq + 3) * LDA + row] = v.w;
            }
            // stage B tile (transposed): rows j0..j0+127
            #pragma unroll
            for (int it = 0; it < 4; ++it) {
                int row = it * 32 + srow;
                float4 v = *(const float4*)(y + (size_t)(j0 + row) * DIM + kc + skq);
                Bs[(skq + 0) * LDB + row] = v.x;
                Bs[(skq + 1) * LDB + row] = v.y;
                Bs[(skq + 2) * LDB + row] = v.z;
                Bs[(skq + 3) * LDB + row] = v.w;
            }
            __syncthreads();
            #pragma unroll 8
            for (int k = 0; k < KB; ++k) {
                float4 a  = *(const float4*)&As[k * LDA + ty * 4];
                float4 b0 = *(const float4*)&Bs[k * LDB + tx * 8];
                float4 b1 = *(const float4*)&Bs[k * LDB + tx * 8 + 4];
                float av[4] = {a.x, a.y, a.z, a.w};
                float bv[8] = {b0.x, b0.y, b0.z, b0.w, b1.x, b1.y, b1.z, b1.w};
                #pragma unroll
                for (int c = 0; c < 4; ++c)
                    #pragma unroll
                    for (int d = 0; d < 8; ++d)
                        acc[c][d] = fmaf(av[c], bv[d], acc[c][d]);
            }
            __syncthreads();
        }

        // fold in y_sq, update running min (x_sq added later; doesn't affect argmin over j)
        float4 q0 = *(const float4*)(y_sq + j0 + tx * 8);
        float4 q1 = *(const float4*)(y_sq + j0 + tx * 8 + 4);
        float qv[8] = {q0.x, q0.y, q0.z, q0.w, q1.x, q1.y, q1.z, q1.w};
        #pragma unroll
        for (int c = 0; c < 4; ++c)
            #pragma unroll
            for (int d = 0; d < 8; ++d)
                minv[c] = fminf(minv[c], qv[d] - 2.f * acc[c][d]);
    }

    // reduce across the 16 tx groups
    #pragma unroll
    for (int c = 0; c < 4; ++c) red[ty * 4 + c][tx] = minv[c];
    __syncthreads();
    if (t < TI) {
        float m = red[t][0];
        #pragma unroll
        for (int xx = 1; xx < 16; ++xx) m = fminf(m, red[t][xx]);
        part[(size_t)(i0 + t) * 2 + jhalf] = m;
    }
}

// ---------------- Kernel C: combine halves, sqrt, argmax ----------------
__global__ __launch_bounds__(1024) void final_kernel(const float* __restrict__ part,
                                                     const float* __restrict__ x_sq,
                                                     float* __restrict__ out) {
    __shared__ float sval[1024];
    __shared__ int   sidx[1024];
    int t = threadIdx.x;
    float best = -__builtin_inff();
    int bidx = 0;
    for (int i = t; i < N_ROWS; i += 1024) {
        float m  = fminf(part[i * 2], part[i * 2 + 1]);
        float sq = x_sq[i] + m;
        float d  = sqrtf(fmaxf(sq, 0.f));
        if (d > best) { best = d; bidx = i; }  // strict > keeps first index within thread
    }
    sval[t] = best;
    sidx[t] = bidx;
    __syncthreads();
    for (int s = 512; s > 0; s >>= 1) {
        if (t < s) {
            float v2 = sval[t + s];
            int   i2 = sidx[t + s];
            if (v2 > sval[t] || (v2 == sval[t] && i2 < sidx[t])) { sval[t] = v2; sidx[t] = i2; }
        }
        __syncthreads();
    }
    if (t == 0) {
        out[0] = sval[0];
        out[1] = (float)sidx[0];
    }
}

extern "C" void kernel_launch(void* const* d_in, const int* in_sizes, int n_in,
                              void* d_out, int out_size, void* d_ws, size_t ws_size,
                              hipStream_t stream) {
    const float* x = (const float*)d_in[0];
    const float* y = (const float*)d_in[1];
    float* out = (float*)d_out;

    float* ws   = (float*)d_ws;
    float* x_sq = ws;                       // N floats
    float* y_sq = ws + N_ROWS;              // M floats
    float* part = ws + N_ROWS + M_ROWS;     // 2*N floats

    rowsq_kernel<<<(N_ROWS + M_ROWS) / 4, 256, 0, stream>>>(x, y, x_sq, y_sq);
    dim3 gridB(N_ROWS / TI, 2);
    minred_kernel<<<gridB, 256, 0, stream>>>(x, y, y_sq, part);
    final_kernel<<<1, 1024, 0, stream>>>(part, x_sq, out);
}

// Round 2
// 542.318 us; speedup vs baseline: 7.3813x; 7.3813x over previous
//
#include <hip/hip_runtime.h>
#include <hip/hip_bf16.h>
#include <math.h>

#define N_ROWS 16384
#define M_ROWS 16384
#define DIM    512
#define JS     8        // j-splits in pass1
#define KCAND  128      // max rescore candidates
#define DELTA  0.15f    // selection margin (bf16 dist err std ~3e-3)

typedef __attribute__((ext_vector_type(8))) short short8;
typedef __attribute__((ext_vector_type(4))) float floatx4;

// ---------------- 1. convert fp32 -> bf16, exact row norms, init control ----------------
__global__ __launch_bounds__(256) void convert_kernel(const float* __restrict__ x, const float* __restrict__ y,
                                                      unsigned short* __restrict__ xh, unsigned short* __restrict__ yh,
                                                      float* __restrict__ x_sq, float* __restrict__ y_sq,
                                                      unsigned int* __restrict__ gmax_bits,
                                                      unsigned int* __restrict__ cnt, int* __restrict__ cand) {
    if (blockIdx.x == 0) {
        if (threadIdx.x < KCAND) cand[threadIdx.x] = 0;
        if (threadIdx.x == 0) { *gmax_bits = 0u; *cnt = 0u; }
    }
    int wave = threadIdx.x >> 6, lane = threadIdx.x & 63;
    int row = blockIdx.x * 4 + wave;
    const float* src; unsigned short* dsth; float* dsq; int r;
    if (row < N_ROWS) { r = row;          src = x; dsth = xh; dsq = x_sq; }
    else              { r = row - N_ROWS; src = y; dsth = yh; dsq = y_sq; }
    const float4* s4 = (const float4*)(src + (size_t)r * DIM);
    float4 a = s4[lane * 2];
    float4 b = s4[lane * 2 + 1];
    float v[8] = {a.x, a.y, a.z, a.w, b.x, b.y, b.z, b.w};
    union { unsigned short us[8]; uint4 u4; } pk;
    float s = 0.f;
    #pragma unroll
    for (int i = 0; i < 8; ++i) {
        s += v[i] * v[i];
        __hip_bfloat16 h = __float2bfloat16(v[i]);
        pk.us[i] = *(unsigned short*)&h;
    }
    *(uint4*)(dsth + (size_t)r * DIM + lane * 8) = pk.u4;
    #pragma unroll
    for (int off = 32; off > 0; off >>= 1) s += __shfl_down(s, off, 64);
    if (lane == 0) dsq[r] = s;
}

// ---------------- 2. pass1: bf16 MFMA, min_j(y_sq[j] - 2 x.y) per row ----------------
// m97 structure: 128x128 tile, BK=32, global_load_lds(16B), 4 waves each 64x64 = 4x4 MFMA frags
__global__ __launch_bounds__(256) void pass1_kernel(const unsigned short* __restrict__ xh,
                                                    const unsigned short* __restrict__ yh,
                                                    const float* __restrict__ y_sq,
                                                    float* __restrict__ part) {
    __shared__ __align__(16) unsigned short As[128 * 32];
    __shared__ __align__(16) unsigned short Bs[128 * 32];
    __shared__ float red[2][128];

    const int t = threadIdx.x;
    const int wid = t >> 6, lane = t & 63;
    const int wm = wid >> 1, wn = wid & 1;          // wave tile: rows wm*64, cols wn*64
    const int col = lane & 15, quad = lane >> 4;    // MFMA lane coords
    const int i0 = blockIdx.x * 128;
    const int jsplit = blockIdx.y;

    // staging role: waves 0,1 -> As halves; waves 2,3 -> Bs halves
    const unsigned short* sSrc = (wid < 2) ? xh : yh;
    unsigned short* sDst = (wid < 2) ? As : Bs;
    const int sBaseRow = (wid & 1) * 64;
    const int sR = lane >> 2;          // row within 16-row group
    const int sK = (lane & 3) * 8;     // bf16 elem offset (16B)

    float minv[16];
    #pragma unroll
    for (int i = 0; i < 16; ++i) minv[i] = __builtin_inff();

    for (int jt = 0; jt < (M_ROWS / JS) / 128; ++jt) {
        const int j0 = jsplit * (M_ROWS / JS) + jt * 128;
        const int gBase = (wid < 2) ? i0 : j0;
        floatx4 acc[4][4];
        #pragma unroll
        for (int mt = 0; mt < 4; ++mt)
            #pragma unroll
            for (int nt = 0; nt < 4; ++nt) acc[mt][nt] = (floatx4){0.f, 0.f, 0.f, 0.f};

        for (int kc = 0; kc < DIM; kc += 32) {
            #pragma unroll
            for (int r = 0; r < 4; ++r) {
                int trow = sBaseRow + r * 16 + sR;
                const unsigned short* gp = sSrc + (size_t)(gBase + trow) * DIM + kc + sK;
                unsigned short* lp = sDst + (sBaseRow + r * 16) * 32;   // wave-uniform; HW adds lane*16B
                __builtin_amdgcn_global_load_lds((const __attribute__((address_space(1))) void*)gp,
                                                 (__attribute__((address_space(3))) void*)lp, 16, 0, 0);
            }
            __syncthreads();
            short8 afr[4], bfr[4];
            #pragma unroll
            for (int mt = 0; mt < 4; ++mt)
                afr[mt] = *(const short8*)&As[(wm * 64 + mt * 16 + col) * 32 + quad * 8];
            #pragma unroll
            for (int nt = 0; nt < 4; ++nt)
                bfr[nt] = *(const short8*)&Bs[(wn * 64 + nt * 16 + col) * 32 + quad * 8];
            #pragma unroll
            for (int mt = 0; mt < 4; ++mt)
                #pragma unroll
                for (int nt = 0; nt < 4; ++nt)
                    acc[mt][nt] = __builtin_amdgcn_mfma_f32_16x16x32_bf16(afr[mt], bfr[nt], acc[mt][nt], 0, 0, 0);
            __syncthreads();
        }
        // fold y_sq, running min over j (x_sq added later; sqrt monotone)
        #pragma unroll
        for (int nt = 0; nt < 4; ++nt) {
            float q = y_sq[j0 + wn * 64 + nt * 16 + col];
            #pragma unroll
            for (int mt = 0; mt < 4; ++mt)
                #pragma unroll
                for (int r = 0; r < 4; ++r)
                    minv[mt * 4 + r] = fminf(minv[mt * 4 + r], q - 2.f * acc[mt][nt][r]);
        }
    }

    // reduce over the 16 col-lanes (C-layout: col = lane&15)
    #pragma unroll
    for (int i = 0; i < 16; ++i) {
        float v = minv[i];
        v = fminf(v, __shfl_xor(v, 1, 64));
        v = fminf(v, __shfl_xor(v, 2, 64));
        v = fminf(v, __shfl_xor(v, 4, 64));
        v = fminf(v, __shfl_xor(v, 8, 64));
        minv[i] = v;
    }
    if (col == 0) {
        #pragma unroll
        for (int mt = 0; mt < 4; ++mt)
            #pragma unroll
            for (int r = 0; r < 4; ++r)
                red[wn][wm * 64 + mt * 16 + quad * 4 + r] = minv[mt * 4 + r];
    }
    __syncthreads();
    if (t < 128)
        part[(size_t)(i0 + t) * JS + jsplit] = fminf(red[0][t], red[1][t]);
}

// ---------------- 3a. per-row approx value + global max ----------------
__global__ __launch_bounds__(1024) void maxred_kernel(const float* __restrict__ part,
                                                      const float* __restrict__ x_sq,
                                                      float* __restrict__ aval,
                                                      unsigned int* __restrict__ gmax_bits) {
    __shared__ float sm[1024];
    int t = threadIdx.x;
    int row = blockIdx.x * 1024 + t;
    float m = part[(size_t)row * JS];
    #pragma unroll
    for (int c = 1; c < JS; ++c) m = fminf(m, part[(size_t)row * JS + c]);
    float v = sqrtf(fmaxf(x_sq[row] + m, 0.f));
    aval[row] = v;
    sm[t] = v;
    __syncthreads();
    for (int s = 512; s > 0; s >>= 1) {
        if (t < s) sm[t] = fmaxf(sm[t], sm[t + s]);
        __syncthreads();
    }
    if (t == 0) atomicMax(gmax_bits, __float_as_uint(sm[0]));  // v>=0: uint order == float order
}

// ---------------- 3b. select candidates within DELTA of max ----------------
__global__ __launch_bounds__(1024) void select_kernel(const float* __restrict__ aval,
                                                      const unsigned int* __restrict__ gmax_bits,
                                                      unsigned int* __restrict__ cnt,
                                                      int* __restrict__ cand) {
    int row = blockIdx.x * 1024 + threadIdx.x;
    float gmax = __uint_as_float(*gmax_bits);
    if (aval[row] >= gmax - DELTA) {
        unsigned s = atomicAdd(cnt, 1u);
        if (s < KCAND) cand[s] = row;
    }
}

// ---------------- 4. exact fp32 rescore of candidates vs all centers ----------------
#define TIr 64
#define LDA 68
#define LDB 132
__global__ __launch_bounds__(256) void rescore_kernel(const float* __restrict__ x, const float* __restrict__ y,
                                                      const float* __restrict__ y_sq,
                                                      const int* __restrict__ cand,
                                                      float* __restrict__ part2) {
    __shared__ __align__(16) float As[32 * LDA];
    __shared__ __align__(16) float Bs[32 * LDB];
    __shared__ float red[TIr][17];

    int t = threadIdx.x;
    int tx = t & 15, ty = t >> 4;
    int i0 = blockIdx.x * TIr;       // candidate slot base (0 or 64)
    int j0 = blockIdx.y * 128;       // center base

    float acc[4][8];
    #pragma unroll
    for (int c = 0; c < 4; ++c)
        #pragma unroll
        for (int d = 0; d < 8; ++d) acc[c][d] = 0.f;

    int srow = t >> 3;
    int skq = (t & 7) * 4;
    int grow0 = cand[i0 + srow];
    int grow1 = cand[i0 + 32 + srow];

    for (int kc = 0; kc < DIM; kc += 32) {
        {
            float4 v = *(const float4*)(x + (size_t)grow0 * DIM + kc + skq);
            As[(skq + 0) * LDA + srow] = v.x;
            As[(skq + 1) * LDA + srow] = v.y;
            As[(skq + 2) * LDA + srow] = v.z;
            As[(skq + 3) * LDA + srow] = v.w;
            v = *(const float4*)(x + (size_t)grow1 * DIM + kc + skq);
            As[(skq + 0) * LDA + 32 + srow] = v.x;
            As[(skq + 1) * LDA + 32 + srow] = v.y;
            As[(skq + 2) * LDA + 32 + srow] = v.z;
            As[(skq + 3) * LDA + 32 + srow] = v.w;
        }
        #pragma unroll
        for (int it = 0; it < 4; ++it) {
            int row = it * 32 + srow;
            float4 v = *(const float4*)(y + (size_t)(j0 + row) * DIM + kc + skq);
            Bs[(skq + 0) * LDB + row] = v.x;
            Bs[(skq + 1) * LDB + row] = v.y;
            Bs[(skq + 2) * LDB + row] = v.z;
            Bs[(skq + 3) * LDB + row] = v.w;
        }
        __syncthreads();
        #pragma unroll 8
        for (int k = 0; k < 32; ++k) {
            float4 a  = *(const float4*)&As[k * LDA + ty * 4];
            float4 b0 = *(const float4*)&Bs[k * LDB + tx * 8];
            float4 b1 = *(const float4*)&Bs[k * LDB + tx * 8 + 4];
            float av[4] = {a.x, a.y, a.z, a.w};
            float bv[8] = {b0.x, b0.y, b0.z, b0.w, b1.x, b1.y, b1.z, b1.w};
            #pragma unroll
            for (int c = 0; c < 4; ++c)
                #pragma unroll
                for (int d = 0; d < 8; ++d)
                    acc[c][d] = fmaf(av[c], bv[d], acc[c][d]);
        }
        __syncthreads();
    }

    float4 q0 = *(const float4*)(y_sq + j0 + tx * 8);
    float4 q1 = *(const float4*)(y_sq + j0 + tx * 8 + 4);
    float qv[8] = {q0.x, q0.y, q0.z, q0.w, q1.x, q1.y, q1.z, q1.w};
    float mv[4] = {__builtin_inff(), __builtin_inff(), __builtin_inff(), __builtin_inff()};
    #pragma unroll
    for (int c = 0; c < 4; ++c)
        #pragma unroll
        for (int d = 0; d < 8; ++d)
            mv[c] = fminf(mv[c], qv[d] - 2.f * acc[c][d]);
    #pragma unroll
    for (int c = 0; c < 4; ++c) red[ty * 4 + c][tx] = mv[c];
    __syncthreads();
    if (t < TIr) {
        float m = red[t][0];
        #pragma unroll
        for (int xx = 1; xx < 16; ++xx) m = fminf(m, red[t][xx]);
        part2[(size_t)(i0 + t) * 128 + blockIdx.y] = m;
    }
}

// ---------------- 5. final: exact min per candidate, argmax with index tie-break ----------------
__global__ __launch_bounds__(128) void final2_kernel(const float* __restrict__ part2,
                                                     const float* __restrict__ x_sq,
                                                     const int* __restrict__ cand,
                                                     const unsigned int* __restrict__ cnt,
                                                     float* __restrict__ out) {
    __shared__ float sv[128];
    __shared__ int si[128];
    int t = threadIdx.x;
    float m = part2[(size_t)t * 128];
    for (int c = 1; c < 128; ++c) m = fminf(m, part2[(size_t)t * 128 + c]);
    unsigned n = *cnt;
    if (n > KCAND) n = KCAND;
    int row = cand[t];
    float v = (t < (int)n) ? sqrtf(fmaxf(x_sq[row] + m, 0.f)) : -__builtin_inff();
    sv[t] = v; si[t] = row;
    __syncthreads();
    for (int s = 64; s > 0; s >>= 1) {
        if (t < s) {
            float v2 = sv[t + s]; int i2 = si[t + s];
            if (v2 > sv[t] || (v2 == sv[t] && i2 < si[t])) { sv[t] = v2; si[t] = i2; }
        }
        __syncthreads();
    }
    if (t == 0) { out[0] = sv[0]; out[1] = (float)si[0]; }
}

extern "C" void kernel_launch(void* const* d_in, const int* in_sizes, int n_in,
                              void* d_out, int out_size, void* d_ws, size_t ws_size,
                              hipStream_t stream) {
    const float* x = (const float*)d_in[0];
    const float* y = (const float*)d_in[1];
    float* out = (float*)d_out;

    char* w = (char*)d_ws;
    unsigned short* xh = (unsigned short*)w;                          // 16 MB
    unsigned short* yh = (unsigned short*)(w + (size_t)16777216);     // 16 MB
    float* x_sq = (float*)(w + (size_t)33554432);                     // N
    float* y_sq = x_sq + N_ROWS;                                      // M
    float* part = y_sq + M_ROWS;                                      // N*JS
    float* aval = part + (size_t)N_ROWS * JS;                         // N
    float* part2 = aval + N_ROWS;                                     // KCAND*128
    int* cand = (int*)(part2 + KCAND * 128);                          // KCAND
    unsigned int* gmax_bits = (unsigned int*)(cand + KCAND);
    unsigned int* cnt = gmax_bits + 1;

    convert_kernel<<<(N_ROWS + M_ROWS) / 4, 256, 0, stream>>>(x, y, xh, yh, x_sq, y_sq, gmax_bits, cnt, cand);
    dim3 g1(N_ROWS / 128, JS);
    pass1_kernel<<<g1, 256, 0, stream>>>(xh, yh, y_sq, part);
    maxred_kernel<<<N_ROWS / 1024, 1024, 0, stream>>>(part, x_sq, aval, gmax_bits);
    select_kernel<<<N_ROWS / 1024, 1024, 0, stream>>>(aval, gmax_bits, cnt, cand);
    dim3 g2(KCAND / TIr, M_ROWS / 128);
    rescore_kernel<<<g2, 256, 0, stream>>>(x, y, y_sq, cand, part2);
    final2_kernel<<<1, 128, 0, stream>>>(part2, x_sq, cand, cnt, out);
}

// Round 3
// 310.234 us; speedup vs baseline: 12.9032x; 1.7481x over previous
//
#include <hip/hip_runtime.h>
#include <hip/hip_fp8.h>
#include <math.h>

#define N_ROWS 16384
#define M_ROWS 16384
#define DIM    512
#define JS     8        // j-splits in pass1
#define KCAND  256      // max rescore candidates
#define DELTA  0.40f    // selection margin (fp8 dist err sigma ~0.03 -> 13 sigma)

typedef __attribute__((ext_vector_type(8))) int   int8v;
typedef __attribute__((ext_vector_type(4))) int   int4v;
typedef __attribute__((ext_vector_type(4))) float floatx4;

// ---------------- 1. convert fp32 -> fp8 e4m3, exact row norms, init control ----------------
__global__ __launch_bounds__(256) void convert_kernel(const float* __restrict__ x, const float* __restrict__ y,
                                                      unsigned char* __restrict__ xh8, unsigned char* __restrict__ yh8,
                                                      float* __restrict__ x_sq, float* __restrict__ y_sq,
                                                      unsigned int* __restrict__ gmax_bits,
                                                      unsigned int* __restrict__ cnt, int* __restrict__ cand) {
    if (blockIdx.x == 0) {
        if (threadIdx.x < KCAND) cand[threadIdx.x] = 0;
        if (threadIdx.x == 0) { *gmax_bits = 0u; *cnt = 0u; }
    }
    int wave = threadIdx.x >> 6, lane = threadIdx.x & 63;
    int row = blockIdx.x * 4 + wave;
    const float* src; unsigned char* dst8; float* dsq; int r;
    if (row < N_ROWS) { r = row;          src = x; dst8 = xh8; dsq = x_sq; }
    else              { r = row - N_ROWS; src = y; dst8 = yh8; dsq = y_sq; }
    const float4* s4 = (const float4*)(src + (size_t)r * DIM);
    float4 a = s4[lane * 2];
    float4 b = s4[lane * 2 + 1];
    float v[8] = {a.x, a.y, a.z, a.w, b.x, b.y, b.z, b.w};
    union { unsigned char b[8]; uint2 u2; } pk;
    float s = 0.f;
    #pragma unroll
    for (int i = 0; i < 8; ++i) {
        s += v[i] * v[i];
        __hip_fp8_e4m3 q(v[i]);
        pk.b[i] = (unsigned char)q.__x;
    }
    *(uint2*)(dst8 + (size_t)r * DIM + lane * 8) = pk.u2;
    #pragma unroll
    for (int off = 32; off > 0; off >>= 1) s += __shfl_down(s, off, 64);
    if (lane == 0) dsq[r] = s;
}

// ---------------- 2. pass1: MX-fp8 MFMA (unit scales), min_j(y_sq[j] - 2 x.y) ----------------
// 128x128 tile, BK=128 bytes, global_load_lds(16B), XOR-8 chunk swizzle, 4 waves x (4x4) 16x16x128 frags
__device__ __forceinline__ int8v read_frag(const unsigned char* base, int row, int quad) {
    int s = row & 7;
    int c0 = ((quad << 1) | 0) ^ s;
    int c1 = ((quad << 1) | 1) ^ s;
    int4v lo = *(const int4v*)(base + row * 128 + c0 * 16);
    int4v hi = *(const int4v*)(base + row * 128 + c1 * 16);
    int8v r;
    r[0] = lo[0]; r[1] = lo[1]; r[2] = lo[2]; r[3] = lo[3];
    r[4] = hi[0]; r[5] = hi[1]; r[6] = hi[2]; r[7] = hi[3];
    return r;
}

__global__ __launch_bounds__(256) void pass1_kernel(const unsigned char* __restrict__ xh8,
                                                    const unsigned char* __restrict__ yh8,
                                                    const float* __restrict__ y_sq,
                                                    float* __restrict__ part) {
    __shared__ __align__(16) unsigned char As[128 * 128];
    __shared__ __align__(16) unsigned char Bs[128 * 128];
    __shared__ float red[2][128];

    const int t = threadIdx.x;
    const int wid = t >> 6, lane = t & 63;
    const int wm = wid >> 1, wn = wid & 1;          // wave tile: rows wm*64, cols wn*64
    const int col = lane & 15, quad = lane >> 4;    // MFMA lane coords (16x16 C-layout)
    const int i0 = blockIdx.x * 128;
    const int jsplit = blockIdx.y;

    // staging role: waves 0,1 -> As halves; waves 2,3 -> Bs halves
    const unsigned char* sSrc = (wid < 2) ? xh8 : yh8;
    unsigned char* sDst = (wid < 2) ? As : Bs;
    const int sBase = (wid & 1) * 64;
    const int rr = lane >> 3;                 // row-in-8-group
    const int p  = lane & 7;                  // chunk position this lane fills
    const int srcChunkOff = ((p ^ rr) << 4);  // swizzled global chunk

    float minv[16];
    #pragma unroll
    for (int i = 0; i < 16; ++i) minv[i] = __builtin_inff();

    for (int jt = 0; jt < (M_ROWS / JS) / 128; ++jt) {
        const int j0 = jsplit * (M_ROWS / JS) + jt * 128;
        const int gBase = (wid < 2) ? i0 : j0;
        floatx4 acc[4][4];
        #pragma unroll
        for (int mt = 0; mt < 4; ++mt)
            #pragma unroll
            for (int nt = 0; nt < 4; ++nt) acc[mt][nt] = (floatx4){0.f, 0.f, 0.f, 0.f};

        for (int kc = 0; kc < DIM; kc += 128) {
            #pragma unroll
            for (int r = 0; r < 8; ++r) {
                const unsigned char* gp = sSrc + (size_t)(gBase + sBase + r * 8 + rr) * DIM + kc + srcChunkOff;
                unsigned char* lp = sDst + (sBase + r * 8) * 128;   // wave-uniform; HW adds lane*16B
                __builtin_amdgcn_global_load_lds((const __attribute__((address_space(1))) void*)gp,
                                                 (__attribute__((address_space(3))) void*)lp, 16, 0, 0);
            }
            __syncthreads();
            int8v afr[4], bfr[4];
            #pragma unroll
            for (int mt = 0; mt < 4; ++mt) afr[mt] = read_frag(As, wm * 64 + mt * 16 + col, quad);
            #pragma unroll
            for (int nt = 0; nt < 4; ++nt) bfr[nt] = read_frag(Bs, wn * 64 + nt * 16 + col, quad);
            #pragma unroll
            for (int mt = 0; mt < 4; ++mt)
                #pragma unroll
                for (int nt = 0; nt < 4; ++nt)
                    acc[mt][nt] = __builtin_amdgcn_mfma_scale_f32_16x16x128_f8f6f4(
                        afr[mt], bfr[nt], acc[mt][nt],
                        0, 0,          // cbsz=fp8(e4m3), blgp=fp8(e4m3)
                        0, 127,        // scale_a opsel, scale_a = E8M0 127 = 1.0
                        0, 127);       // scale_b opsel, scale_b = 1.0
            __syncthreads();
        }
        // fold y_sq, running min over j (x_sq added later; sqrt monotone)
        #pragma unroll
        for (int nt = 0; nt < 4; ++nt) {
            float q = y_sq[j0 + wn * 64 + nt * 16 + col];
            #pragma unroll
            for (int mt = 0; mt < 4; ++mt)
                #pragma unroll
                for (int r = 0; r < 4; ++r)
                    minv[mt * 4 + r] = fminf(minv[mt * 4 + r], q - 2.f * acc[mt][nt][r]);
        }
    }

    // reduce over the 16 col-lanes (C-layout: col = lane&15, row = quad*4+r)
    #pragma unroll
    for (int i = 0; i < 16; ++i) {
        float v = minv[i];
        v = fminf(v, __shfl_xor(v, 1, 64));
        v = fminf(v, __shfl_xor(v, 2, 64));
        v = fminf(v, __shfl_xor(v, 4, 64));
        v = fminf(v, __shfl_xor(v, 8, 64));
        minv[i] = v;
    }
    if (col == 0) {
        #pragma unroll
        for (int mt = 0; mt < 4; ++mt)
            #pragma unroll
            for (int r = 0; r < 4; ++r)
                red[wn][wm * 64 + mt * 16 + quad * 4 + r] = minv[mt * 4 + r];
    }
    __syncthreads();
    if (t < 128)
        part[(size_t)(i0 + t) * JS + jsplit] = fminf(red[0][t], red[1][t]);
}

// ---------------- 3a. per-row approx value + global max ----------------
__global__ __launch_bounds__(1024) void maxred_kernel(const float* __restrict__ part,
                                                      const float* __restrict__ x_sq,
                                                      float* __restrict__ aval,
                                                      unsigned int* __restrict__ gmax_bits) {
    __shared__ float sm[1024];
    int t = threadIdx.x;
    int row = blockIdx.x * 1024 + t;
    float m = part[(size_t)row * JS];
    #pragma unroll
    for (int c = 1; c < JS; ++c) m = fminf(m, part[(size_t)row * JS + c]);
    float v = sqrtf(fmaxf(x_sq[row] + m, 0.f));
    aval[row] = v;
    sm[t] = v;
    __syncthreads();
    for (int s = 512; s > 0; s >>= 1) {
        if (t < s) sm[t] = fmaxf(sm[t], sm[t + s]);
        __syncthreads();
    }
    if (t == 0) atomicMax(gmax_bits, __float_as_uint(sm[0]));  // v>=0: uint order == float order
}

// ---------------- 3b. select candidates within DELTA of max ----------------
__global__ __launch_bounds__(1024) void select_kernel(const float* __restrict__ aval,
                                                      const unsigned int* __restrict__ gmax_bits,
                                                      unsigned int* __restrict__ cnt,
                                                      int* __restrict__ cand) {
    int row = blockIdx.x * 1024 + threadIdx.x;
    float gmax = __uint_as_float(*gmax_bits);
    if (aval[row] >= gmax - DELTA) {
        unsigned s = atomicAdd(cnt, 1u);
        if (s < KCAND) cand[s] = row;
    }
}

// ---------------- 4. exact fp32 rescore of candidates vs all centers ----------------
#define TIr 64
#define LDA 68
#define LDB 132
__global__ __launch_bounds__(256) void rescore_kernel(const float* __restrict__ x, const float* __restrict__ y,
                                                      const float* __restrict__ y_sq,
                                                      const int* __restrict__ cand,
                                                      const unsigned int* __restrict__ cnt,
                                                      float* __restrict__ part2) {
    __shared__ __align__(16) float As[32 * LDA];
    __shared__ __align__(16) float Bs[32 * LDB];
    __shared__ float red[TIr][17];

    int t = threadIdx.x;
    int tx = t & 15, ty = t >> 4;
    int i0 = blockIdx.x * TIr;       // candidate slot base
    int j0 = blockIdx.y * 128;       // center base

    if ((unsigned)i0 >= *cnt) return;   // uniform early-exit: unused candidate blocks

    float acc[4][8];
    #pragma unroll
    for (int c = 0; c < 4; ++c)
        #pragma unroll
        for (int d = 0; d < 8; ++d) acc[c][d] = 0.f;

    int srow = t >> 3;
    int skq = (t & 7) * 4;
    int grow0 = cand[i0 + srow];
    int grow1 = cand[i0 + 32 + srow];

    for (int kc = 0; kc < DIM; kc += 32) {
        {
            float4 v = *(const float4*)(x + (size_t)grow0 * DIM + kc + skq);
            As[(skq + 0) * LDA + srow] = v.x;
            As[(skq + 1) * LDA + srow] = v.y;
            As[(skq + 2) * LDA + srow] = v.z;
            As[(skq + 3) * LDA + srow] = v.w;
            v = *(const float4*)(x + (size_t)grow1 * DIM + kc + skq);
            As[(skq + 0) * LDA + 32 + srow] = v.x;
            As[(skq + 1) * LDA + 32 + srow] = v.y;
            As[(skq + 2) * LDA + 32 + srow] = v.z;
            As[(skq + 3) * LDA + 32 + srow] = v.w;
        }
        #pragma unroll
        for (int it = 0; it < 4; ++it) {
            int row = it * 32 + srow;
            float4 v = *(const float4*)(y + (size_t)(j0 + row) * DIM + kc + skq);
            Bs[(skq + 0) * LDB + row] = v.x;
            Bs[(skq + 1) * LDB + row] = v.y;
            Bs[(skq + 2) * LDB + row] = v.z;
            Bs[(skq + 3) * LDB + row] = v.w;
        }
        __syncthreads();
        #pragma unroll 8
        for (int k = 0; k < 32; ++k) {
            float4 a  = *(const float4*)&As[k * LDA + ty * 4];
            float4 b0 = *(const float4*)&Bs[k * LDB + tx * 8];
            float4 b1 = *(const float4*)&Bs[k * LDB + tx * 8 + 4];
            float av[4] = {a.x, a.y, a.z, a.w};
            float bv[8] = {b0.x, b0.y, b0.z, b0.w, b1.x, b1.y, b1.z, b1.w};
            #pragma unroll
            for (int c = 0; c < 4; ++c)
                #pragma unroll
                for (int d = 0; d < 8; ++d)
                    acc[c][d] = fmaf(av[c], bv[d], acc[c][d]);
        }
        __syncthreads();
    }

    float4 q0 = *(const float4*)(y_sq + j0 + tx * 8);
    float4 q1 = *(const float4*)(y_sq + j0 + tx * 8 + 4);
    float qv[8] = {q0.x, q0.y, q0.z, q0.w, q1.x, q1.y, q1.z, q1.w};
    float mv[4] = {__builtin_inff(), __builtin_inff(), __builtin_inff(), __builtin_inff()};
    #pragma unroll
    for (int c = 0; c < 4; ++c)
        #pragma unroll
        for (int d = 0; d < 8; ++d)
            mv[c] = fminf(mv[c], qv[d] - 2.f * acc[c][d]);
    #pragma unroll
    for (int c = 0; c < 4; ++c) red[ty * 4 + c][tx] = mv[c];
    __syncthreads();
    if (t < TIr) {
        float m = red[t][0];
        #pragma unroll
        for (int xx = 1; xx < 16; ++xx) m = fminf(m, red[t][xx]);
        part2[(size_t)(i0 + t) * 128 + blockIdx.y] = m;
    }
}

// ---------------- 5. final: exact min per candidate, argmax with index tie-break ----------------
__global__ __launch_bounds__(256) void final2_kernel(const float* __restrict__ part2,
                                                     const float* __restrict__ x_sq,
                                                     const int* __restrict__ cand,
                                                     const unsigned int* __restrict__ cnt,
                                                     float* __restrict__ out) {
    __shared__ float sv[256];
    __shared__ int si[256];
    int t = threadIdx.x;
    const float4* p4 = (const float4*)(part2 + (size_t)t * 128);
    float m = __builtin_inff();
    for (int c = 0; c < 32; ++c) {
        float4 v = p4[c];
        m = fminf(m, fminf(fminf(v.x, v.y), fminf(v.z, v.w)));
    }
    unsigned n = *cnt;
    if (n > KCAND) n = KCAND;
    int row = cand[t];
    float v = (t < (int)n) ? sqrtf(fmaxf(x_sq[row] + m, 0.f)) : -__builtin_inff();
    sv[t] = v; si[t] = row;
    __syncthreads();
    for (int s = 128; s > 0; s >>= 1) {
        if (t < s) {
            float v2 = sv[t + s]; int i2 = si[t + s];
            if (v2 > sv[t] || (v2 == sv[t] && i2 < si[t])) { sv[t] = v2; si[t] = i2; }
        }
        __syncthreads();
    }
    if (t == 0) { out[0] = sv[0]; out[1] = (float)si[0]; }
}

extern "C" void kernel_launch(void* const* d_in, const int* in_sizes, int n_in,
                              void* d_out, int out_size, void* d_ws, size_t ws_size,
                              hipStream_t stream) {
    const float* x = (const float*)d_in[0];
    const float* y = (const float*)d_in[1];
    float* out = (float*)d_out;

    char* w = (char*)d_ws;
    unsigned char* xh8 = (unsigned char*)w;                           // 8 MB
    unsigned char* yh8 = (unsigned char*)(w + (size_t)8388608);       // 8 MB
    float* x_sq = (float*)(w + (size_t)16777216);                     // N
    float* y_sq = x_sq + N_ROWS;                                      // M
    float* part = y_sq + M_ROWS;                                      // N*JS
    float* aval = part + (size_t)N_ROWS * JS;                         // N
    float* part2 = aval + N_ROWS;                                     // KCAND*128
    int* cand = (int*)(part2 + KCAND * 128);                          // KCAND
    unsigned int* gmax_bits = (unsigned int*)(cand + KCAND);
    unsigned int* cnt = gmax_bits + 1;

    convert_kernel<<<(N_ROWS + M_ROWS) / 4, 256, 0, stream>>>(x, y, xh8, yh8, x_sq, y_sq, gmax_bits, cnt, cand);
    dim3 g1(N_ROWS / 128, JS);
    pass1_kernel<<<g1, 256, 0, stream>>>(xh8, yh8, y_sq, part);
    maxred_kernel<<<N_ROWS / 1024, 1024, 0, stream>>>(part, x_sq, aval, gmax_bits);
    select_kernel<<<N_ROWS / 1024, 1024, 0, stream>>>(aval, gmax_bits, cnt, cand);
    dim3 g2(KCAND / TIr, M_ROWS / 128);
    rescore_kernel<<<g2, 256, 0, stream>>>(x, y, y_sq, cand, cnt, part2);
    final2_kernel<<<1, 256, 0, stream>>>(part2, x_sq, cand, cnt, out);
}